// Round 1
// baseline (187.333 us; speedup 1.0000x reference)
//
#include <hip/hip_runtime.h>
#include <hip/hip_bf16.h>

#define B_ 8
#define S_ 2048
#define E_ 1024
#define H_ 64
#define LOG2E 1.4426950408889634f

typedef __attribute__((ext_vector_type(8))) short short8;
typedef __attribute__((ext_vector_type(4))) float floatx4;

static __device__ __forceinline__ short f2bf(float f) {
    union { float f; unsigned u; } a; a.f = f;
    unsigned r = a.u + 0x7FFF + ((a.u >> 16) & 1);
    return (short)(r >> 16);
}

// ---------------------------------------------------------------------------
// Kernel 1: convert + transpose weights into Wt[192][1024] bf16 (h-major)
// h 0..63 -> wq, 64..127 -> wk, 128..191 -> wv
// ---------------------------------------------------------------------------
__global__ void wprep_kernel(const float* __restrict__ wq,
                             const float* __restrict__ wk,
                             const float* __restrict__ wv,
                             short* __restrict__ Wt) {
    int tid = blockIdx.x * blockDim.x + threadIdx.x;   // 0 .. 192*1024-1
    int h = tid >> 10;
    int e = tid & 1023;
    const float* src = (h < 64) ? wq : ((h < 128) ? wk : wv);
    Wt[tid] = f2bf(src[e * H_ + (h & 63)]);
}

// ---------------------------------------------------------------------------
// Kernel 2: QKV projection. M=16384 rows, K=1024, N=192.
// Block = 256 thr (4 waves); block covers 64 rows, each wave 16 rows x 192 cols.
// A-frags: f32 x loaded + converted in-register. B-frags: contiguous short8
// from Wt (L2-resident). No LDS.
// ---------------------------------------------------------------------------
__global__ __launch_bounds__(256) void qkv_proj_kernel(
        const float* __restrict__ x, const short* __restrict__ Wt,
        short* __restrict__ qb, short* __restrict__ kb, short* __restrict__ vb) {
    int lane = threadIdx.x & 63;
    int w    = threadIdx.x >> 6;
    int lrow = lane & 15;
    int lgrp = lane >> 4;
    int lk   = lgrp * 8;

    int rowbase = blockIdx.x * 64 + w * 16;
    const float* xrow = x + (size_t)(rowbase + lrow) * E_ + lk;

    floatx4 acc[12];
#pragma unroll
    for (int i = 0; i < 12; i++) acc[i] = (floatx4){0.f, 0.f, 0.f, 0.f};

    for (int ks = 0; ks < E_ / 32; ks++) {
        floatx4 xa0 = *(const floatx4*)(xrow + ks * 32);
        floatx4 xa1 = *(const floatx4*)(xrow + ks * 32 + 4);
        short8 a;
        a[0] = f2bf(xa0[0]); a[1] = f2bf(xa0[1]);
        a[2] = f2bf(xa0[2]); a[3] = f2bf(xa0[3]);
        a[4] = f2bf(xa1[0]); a[5] = f2bf(xa1[1]);
        a[6] = f2bf(xa1[2]); a[7] = f2bf(xa1[3]);
#pragma unroll
        for (int nf = 0; nf < 12; nf++) {
            const short* wp = Wt + (size_t)(nf * 16 + lrow) * E_ + ks * 32 + lk;
            short8 b = *(const short8*)wp;
            acc[nf] = __builtin_amdgcn_mfma_f32_16x16x32_bf16(a, b, acc[nf], 0, 0, 0);
        }
    }

    int rrow = lgrp * 4;
#pragma unroll
    for (int nf = 0; nf < 12; nf++) {
        int col = nf * 16 + lrow;
        short* dst = (col < 64) ? qb : ((col < 128) ? kb : vb);
        int cc = col & 63;
#pragma unroll
        for (int j = 0; j < 4; j++) {
            dst[(size_t)(rowbase + rrow + j) * H_ + cc] = f2bf(acc[nf][j]);
        }
    }
}

// ---------------------------------------------------------------------------
// Kernel 3: causal flash attention. Grid = 8 batches x 32 q-tiles of 64 rows.
// 4 waves/block, wave owns 16 q rows. KVBLK=64. scale = 1/32 (E^-0.5).
// ---------------------------------------------------------------------------
__global__ __launch_bounds__(256) void attn_kernel(
        const short* __restrict__ qb, const short* __restrict__ kb,
        const short* __restrict__ vb, float* __restrict__ out) {
    __shared__ __align__(16) short Vt[64][72];      // V transposed [h][kv], padded
    __shared__ __align__(16) short Ps[4][16][72];   // per-wave P tile [q][kv], padded

    int tid  = threadIdx.x;
    int lane = tid & 63;
    int w    = tid >> 6;
    int lrow = lane & 15;
    int lgrp = lane >> 4;
    int lk   = lgrp * 8;

    int qt = blockIdx.x & 31;
    int b  = blockIdx.x >> 5;
    int q0 = qt * 64;
    int qrow = q0 + w * 16 + lrow;   // A-frag row this lane loads

    const short* qptr = qb + ((size_t)b * S_ + qrow) * H_;
    short8 qf0 = *(const short8*)(qptr + lk);
    short8 qf1 = *(const short8*)(qptr + 32 + lk);

    floatx4 O[4];
#pragma unroll
    for (int nf = 0; nf < 4; nf++) O[nf] = (floatx4){0.f, 0.f, 0.f, 0.f};
    float m[4], lsum[4];
#pragma unroll
    for (int j = 0; j < 4; j++) { m[j] = -1e30f; lsum[j] = 0.f; }

    const short* kbase = kb + (size_t)b * S_ * H_;
    const short* vbase = vb + (size_t)b * S_ * H_;

    for (int t = 0; t <= qt; t++) {
        int kv0 = t * 64;
        __syncthreads();   // previous tile's Vt reads done before overwrite

        // --- stage V tile transposed into LDS ---
        {
            int kvr = tid >> 2;
            int hs  = (tid & 3) * 16;
            const short* vp = vbase + (size_t)(kv0 + kvr) * H_ + hs;
            short8 v0 = *(const short8*)vp;
            short8 v1 = *(const short8*)(vp + 8);
#pragma unroll
            for (int c = 0; c < 8; c++) Vt[hs + c][kvr] = v0[c];
#pragma unroll
            for (int c = 0; c < 8; c++) Vt[hs + 8 + c][kvr] = v1[c];
        }

        // --- S = (Q K^T) * scale ---
        floatx4 s[4];
#pragma unroll
        for (int nf = 0; nf < 4; nf++) {
            const short* kp = kbase + (size_t)(kv0 + nf * 16 + lrow) * H_ + lk;
            short8 b0 = *(const short8*)kp;
            short8 b1 = *(const short8*)(kp + 32);
            floatx4 a = (floatx4){0.f, 0.f, 0.f, 0.f};
            a = __builtin_amdgcn_mfma_f32_16x16x32_bf16(qf0, b0, a, 0, 0, 0);
            a = __builtin_amdgcn_mfma_f32_16x16x32_bf16(qf1, b1, a, 0, 0, 0);
            s[nf] = a;
        }
#pragma unroll
        for (int nf = 0; nf < 4; nf++)
#pragma unroll
            for (int j = 0; j < 4; j++) s[nf][j] *= 0.03125f;

        // --- causal mask (diagonal tile only) ---
        if (t == qt) {
#pragma unroll
            for (int nf = 0; nf < 4; nf++) {
                int kvidx = kv0 + nf * 16 + lrow;
#pragma unroll
                for (int j = 0; j < 4; j++) {
                    int qidx = q0 + w * 16 + lgrp * 4 + j;
                    if (kvidx > qidx) s[nf][j] = -1e30f;
                }
            }
        }

        // --- online softmax (rows live in 16-lane groups) ---
        float alpha[4];
#pragma unroll
        for (int j = 0; j < 4; j++) {
            float mx = fmaxf(fmaxf(s[0][j], s[1][j]), fmaxf(s[2][j], s[3][j]));
#pragma unroll
            for (int off = 1; off < 16; off <<= 1)
                mx = fmaxf(mx, __shfl_xor(mx, off));
            float mn = fmaxf(m[j], mx);
            alpha[j] = exp2f((m[j] - mn) * LOG2E);
            m[j] = mn;
            float ps = 0.f;
#pragma unroll
            for (int nf = 0; nf < 4; nf++) {
                float p = exp2f((s[nf][j] - mn) * LOG2E);
                s[nf][j] = p;
                ps += p;
            }
#pragma unroll
            for (int off = 1; off < 16; off <<= 1)
                ps += __shfl_xor(ps, off);
            lsum[j] = lsum[j] * alpha[j] + ps;
        }

        // --- write P (bf16) to LDS, rescale O ---
#pragma unroll
        for (int nf = 0; nf < 4; nf++) {
#pragma unroll
            for (int j = 0; j < 4; j++) {
                Ps[w][lgrp * 4 + j][nf * 16 + lrow] = f2bf(s[nf][j]);
                O[nf][j] *= alpha[j];
            }
        }
        __syncthreads();   // Vt staged + Ps visible

        // --- O += P V ---
        short8 pa0 = *(const short8*)&Ps[w][lrow][lk];
        short8 pa1 = *(const short8*)&Ps[w][lrow][32 + lk];
#pragma unroll
        for (int nf = 0; nf < 4; nf++) {
            short8 vb0 = *(const short8*)&Vt[nf * 16 + lrow][lk];
            short8 vb1 = *(const short8*)&Vt[nf * 16 + lrow][32 + lk];
            O[nf] = __builtin_amdgcn_mfma_f32_16x16x32_bf16(pa0, vb0, O[nf], 0, 0, 0);
            O[nf] = __builtin_amdgcn_mfma_f32_16x16x32_bf16(pa1, vb1, O[nf], 0, 0, 0);
        }
    }

    // --- epilogue: O / l -> out (f32) ---
#pragma unroll
    for (int nf = 0; nf < 4; nf++) {
#pragma unroll
        for (int j = 0; j < 4; j++) {
            float o = O[nf][j] / lsum[j];
            out[((size_t)b * S_ + q0 + w * 16 + lgrp * 4 + j) * H_ + nf * 16 + lrow] = o;
        }
    }
}

// ---------------------------------------------------------------------------
extern "C" void kernel_launch(void* const* d_in, const int* in_sizes, int n_in,
                              void* d_out, int out_size, void* d_ws, size_t ws_size,
                              hipStream_t stream) {
    const float* x  = (const float*)d_in[0];
    const float* wq = (const float*)d_in[1];
    const float* wk = (const float*)d_in[2];
    const float* wv = (const float*)d_in[3];
    float* out = (float*)d_out;

    char* ws = (char*)d_ws;
    const size_t WT_BYTES = (size_t)192 * 1024 * 2;          // 393216
    const size_t QKV_BYTES = (size_t)B_ * S_ * H_ * 2;       // 2097152 each
    short* Wt = (short*)ws;
    short* qb = (short*)(ws + WT_BYTES);
    short* kb = (short*)(ws + WT_BYTES + QKV_BYTES);
    short* vb = (short*)(ws + WT_BYTES + 2 * QKV_BYTES);

    wprep_kernel<<<768, 256, 0, stream>>>(wq, wk, wv, Wt);
    qkv_proj_kernel<<<256, 256, 0, stream>>>(x, Wt, qb, kb, vb);
    attn_kernel<<<256, 256, 0, stream>>>(qb, kb, vb, out);
}

// Round 2
// 112.232 us; speedup vs baseline: 1.6692x; 1.6692x over previous
//
#include <hip/hip_runtime.h>
#include <hip/hip_bf16.h>

#define B_ 8
#define S_ 2048
#define E_ 1024
#define H_ 64
#define LOG2E 1.4426950408889634f

typedef __attribute__((ext_vector_type(8))) short short8;
typedef __attribute__((ext_vector_type(4))) float floatx4;
typedef unsigned int u32;

static __device__ __forceinline__ short f2bf(float f) {
    union { float f; unsigned u; } a; a.f = f;
    unsigned r = a.u + 0x7FFF + ((a.u >> 16) & 1);
    return (short)(r >> 16);
}

static __device__ __forceinline__ void gl_lds16(const short* g, short* l) {
    __builtin_amdgcn_global_load_lds(
        (const __attribute__((address_space(1))) u32*)(g),
        (__attribute__((address_space(3))) u32*)(l),
        16, 0, 0);
}

// ---------------------------------------------------------------------------
// Kernel 1: weights -> bf16, tiled per K-panel [16][192][64] with XOR chunk
// swizzle pre-applied in global so global_load_lds(linear) + swizzled ds_read
// is conflict-free.  Wt element (ks, row, col): addr = ks*12288 + row*64 +
// ((col>>3)^(row&7))*8 + (col&7).   row = m*64+h (m: 0=q,1=k,2=v), col = e&63.
// ---------------------------------------------------------------------------
__global__ __launch_bounds__(256) void wprep_kernel(
        const float* __restrict__ wq, const float* __restrict__ wk,
        const float* __restrict__ wv, short* __restrict__ Wt) {
    __shared__ short Ws[64][73];
    int bid = blockIdx.x;            // 48 blocks: m = bid>>4, e-chunk = bid&15
    int m  = bid >> 4;
    int ec = bid & 15;
    const float* src = (m == 0) ? wq : ((m == 1) ? wk : wv);
    int t = threadIdx.x;

    // load 64 e-rows x 64 h, coalesced
    {
        int er = t >> 2;
        int hc = (t & 3) * 16;
        const float* sp = src + (size_t)(ec * 64 + er) * H_ + hc;
        floatx4 v0 = *(const floatx4*)(sp);
        floatx4 v1 = *(const floatx4*)(sp + 4);
        floatx4 v2 = *(const floatx4*)(sp + 8);
        floatx4 v3 = *(const floatx4*)(sp + 12);
#pragma unroll
        for (int j = 0; j < 4; j++) Ws[er][hc + j]      = f2bf(v0[j]);
#pragma unroll
        for (int j = 0; j < 4; j++) Ws[er][hc + 4 + j]  = f2bf(v1[j]);
#pragma unroll
        for (int j = 0; j < 4; j++) Ws[er][hc + 8 + j]  = f2bf(v2[j]);
#pragma unroll
        for (int j = 0; j < 4; j++) Ws[er][hc + 12 + j] = f2bf(v3[j]);
    }
    __syncthreads();

    // write out transposed + swizzled, 16B chunks
    {
        int h  = t >> 2;
        int eo = (t & 3) * 16;
        int row = m * 64 + h;
        short* obase = Wt + (size_t)ec * 12288 + (size_t)row * 64;
#pragma unroll
        for (int g = 0; g < 2; g++) {
            short8 o;
#pragma unroll
            for (int jj = 0; jj < 8; jj++) o[jj] = Ws[eo + g * 8 + jj][h];
            int chunk = ((eo >> 3) + g) ^ (row & 7);
            *(short8*)(obase + chunk * 8) = o;
        }
    }
}

// ---------------------------------------------------------------------------
// Kernel 2: QKV projection GEMM.  M=16384, K=1024, N=192.
// Block = 256 thr (4 waves), BM=32 rows, full N.  Wave = 16 rows x 96 cols.
// BK=64, W staged in LDS (double-buffered, global_load_lds w=16, pre-swizzled
// layout).  x per-lane f32 loads, prefetched 1 step ahead, converted to bf16.
// Grid = 512 -> 2 blocks/CU.
// ---------------------------------------------------------------------------
__global__ __launch_bounds__(256) void qkv_proj_kernel(
        const float* __restrict__ x, const short* __restrict__ Wt,
        short* __restrict__ qb, short* __restrict__ kb, short* __restrict__ vb) {
    __shared__ short Wlds[2][12288];   // 2 x 24 KB

    int tid  = threadIdx.x;
    int lane = tid & 63;
    int w    = tid >> 6;
    int lrow = lane & 15;
    int lgrp = lane >> 4;
    int lk   = lgrp * 8;

    int wrow = (w >> 1) * 16;          // 0 / 16
    int wcol = (w & 1) * 96;           // 0 / 96
    int rowbase = blockIdx.x * 32;

    const float* xp = x + (size_t)(rowbase + wrow + lrow) * E_ + lk;

    floatx4 acc[6];
#pragma unroll
    for (int i = 0; i < 6; i++) acc[i] = (floatx4){0.f, 0.f, 0.f, 0.f};

    // stage panel 0
    {
        const short* p = Wt + (size_t)0 * 12288 + w * 512 + lane * 8;
        short* l = &Wlds[0][w * 512];
#pragma unroll
        for (int i = 0; i < 6; i++) gl_lds16(p + i * 2048, l + i * 2048);
    }
    // prefetch x panel 0
    floatx4 xa0 = *(const floatx4*)(xp);
    floatx4 xa1 = *(const floatx4*)(xp + 4);
    floatx4 xb0 = *(const floatx4*)(xp + 32);
    floatx4 xb1 = *(const floatx4*)(xp + 36);

    __syncthreads();   // panel 0 staged

    for (int ks = 0; ks < 16; ks++) {
        int cur = ks & 1;
        // issue next panel stage (overlaps with compute below)
        if (ks < 15) {
            const short* p = Wt + (size_t)(ks + 1) * 12288 + w * 512 + lane * 8;
            short* l = &Wlds[cur ^ 1][w * 512];
#pragma unroll
            for (int i = 0; i < 6; i++) gl_lds16(p + i * 2048, l + i * 2048);
        }
        // convert current x to A-frags
        short8 a0, a1;
        a0[0] = f2bf(xa0[0]); a0[1] = f2bf(xa0[1]); a0[2] = f2bf(xa0[2]); a0[3] = f2bf(xa0[3]);
        a0[4] = f2bf(xa1[0]); a0[5] = f2bf(xa1[1]); a0[6] = f2bf(xa1[2]); a0[7] = f2bf(xa1[3]);
        a1[0] = f2bf(xb0[0]); a1[1] = f2bf(xb0[1]); a1[2] = f2bf(xb0[2]); a1[3] = f2bf(xb0[3]);
        a1[4] = f2bf(xb1[0]); a1[5] = f2bf(xb1[1]); a1[6] = f2bf(xb1[2]); a1[7] = f2bf(xb1[3]);
        // prefetch next x
        if (ks < 15) {
            const float* xn = xp + (ks + 1) * 64;
            xa0 = *(const floatx4*)(xn);
            xa1 = *(const floatx4*)(xn + 4);
            xb0 = *(const floatx4*)(xn + 32);
            xb1 = *(const floatx4*)(xn + 36);
        }
        // compute from current buffer
        const short* base = &Wlds[cur][0];
#pragma unroll
        for (int nf = 0; nf < 6; nf++) {
            int row = wcol + nf * 16 + lrow;
            int c0  = lgrp ^ (row & 7);
            short8 b0 = *(const short8*)(base + row * 64 + c0 * 8);
            short8 b1 = *(const short8*)(base + row * 64 + (c0 ^ 4) * 8);
            acc[nf] = __builtin_amdgcn_mfma_f32_16x16x32_bf16(a0, b0, acc[nf], 0, 0, 0);
            acc[nf] = __builtin_amdgcn_mfma_f32_16x16x32_bf16(a1, b1, acc[nf], 0, 0, 0);
        }
        __syncthreads();   // drain stage(ks+1), release buf[cur] readers
    }

    // epilogue
    int rrow = lgrp * 4;
#pragma unroll
    for (int nf = 0; nf < 6; nf++) {
        int col = wcol + nf * 16 + lrow;
        short* dst = (col < 64) ? qb : ((col < 128) ? kb : vb);
        int cc = col & 63;
#pragma unroll
        for (int j = 0; j < 4; j++) {
            dst[(size_t)(rowbase + wrow + rrow + j) * H_ + cc] = f2bf(acc[nf][j]);
        }
    }
}

// ---------------------------------------------------------------------------
// Kernel 3: causal flash attention (unchanged this round).
// Grid = 8 batches x 32 q-tiles of 64 rows, 4 waves/block, KVBLK=64.
// ---------------------------------------------------------------------------
__global__ __launch_bounds__(256) void attn_kernel(
        const short* __restrict__ qb, const short* __restrict__ kb,
        const short* __restrict__ vb, float* __restrict__ out) {
    __shared__ __align__(16) short Vt[64][72];
    __shared__ __align__(16) short Ps[4][16][72];

    int tid  = threadIdx.x;
    int lane = tid & 63;
    int w    = tid >> 6;
    int lrow = lane & 15;
    int lgrp = lane >> 4;
    int lk   = lgrp * 8;

    int qt = blockIdx.x & 31;
    int b  = blockIdx.x >> 5;
    int q0 = qt * 64;
    int qrow = q0 + w * 16 + lrow;

    const short* qptr = qb + ((size_t)b * S_ + qrow) * H_;
    short8 qf0 = *(const short8*)(qptr + lk);
    short8 qf1 = *(const short8*)(qptr + 32 + lk);

    floatx4 O[4];
#pragma unroll
    for (int nf = 0; nf < 4; nf++) O[nf] = (floatx4){0.f, 0.f, 0.f, 0.f};
    float m[4], lsum[4];
#pragma unroll
    for (int j = 0; j < 4; j++) { m[j] = -1e30f; lsum[j] = 0.f; }

    const short* kbase = kb + (size_t)b * S_ * H_;
    const short* vbase = vb + (size_t)b * S_ * H_;

    for (int t = 0; t <= qt; t++) {
        int kv0 = t * 64;
        __syncthreads();

        {
            int kvr = tid >> 2;
            int hs  = (tid & 3) * 16;
            const short* vp = vbase + (size_t)(kv0 + kvr) * H_ + hs;
            short8 v0 = *(const short8*)vp;
            short8 v1 = *(const short8*)(vp + 8);
#pragma unroll
            for (int c = 0; c < 8; c++) Vt[hs + c][kvr] = v0[c];
#pragma unroll
            for (int c = 0; c < 8; c++) Vt[hs + 8 + c][kvr] = v1[c];
        }

        floatx4 s[4];
#pragma unroll
        for (int nf = 0; nf < 4; nf++) {
            const short* kp = kbase + (size_t)(kv0 + nf * 16 + lrow) * H_ + lk;
            short8 b0 = *(const short8*)kp;
            short8 b1 = *(const short8*)(kp + 32);
            floatx4 a = (floatx4){0.f, 0.f, 0.f, 0.f};
            a = __builtin_amdgcn_mfma_f32_16x16x32_bf16(qf0, b0, a, 0, 0, 0);
            a = __builtin_amdgcn_mfma_f32_16x16x32_bf16(qf1, b1, a, 0, 0, 0);
            s[nf] = a;
        }
#pragma unroll
        for (int nf = 0; nf < 4; nf++)
#pragma unroll
            for (int j = 0; j < 4; j++) s[nf][j] *= 0.03125f;

        if (t == qt) {
#pragma unroll
            for (int nf = 0; nf < 4; nf++) {
                int kvidx = kv0 + nf * 16 + lrow;
#pragma unroll
                for (int j = 0; j < 4; j++) {
                    int qidx = q0 + w * 16 + lgrp * 4 + j;
                    if (kvidx > qidx) s[nf][j] = -1e30f;
                }
            }
        }

        float alpha[4];
#pragma unroll
        for (int j = 0; j < 4; j++) {
            float mx = fmaxf(fmaxf(s[0][j], s[1][j]), fmaxf(s[2][j], s[3][j]));
#pragma unroll
            for (int off = 1; off < 16; off <<= 1)
                mx = fmaxf(mx, __shfl_xor(mx, off));
            float mn = fmaxf(m[j], mx);
            alpha[j] = exp2f((m[j] - mn) * LOG2E);
            m[j] = mn;
            float ps = 0.f;
#pragma unroll
            for (int nf = 0; nf < 4; nf++) {
                float p = exp2f((s[nf][j] - mn) * LOG2E);
                s[nf][j] = p;
                ps += p;
            }
#pragma unroll
            for (int off = 1; off < 16; off <<= 1)
                ps += __shfl_xor(ps, off);
            lsum[j] = lsum[j] * alpha[j] + ps;
        }

#pragma unroll
        for (int nf = 0; nf < 4; nf++) {
#pragma unroll
            for (int j = 0; j < 4; j++) {
                Ps[w][lgrp * 4 + j][nf * 16 + lrow] = f2bf(s[nf][j]);
                O[nf][j] *= alpha[j];
            }
        }
        __syncthreads();

        short8 pa0 = *(const short8*)&Ps[w][lrow][lk];
        short8 pa1 = *(const short8*)&Ps[w][lrow][32 + lk];
#pragma unroll
        for (int nf = 0; nf < 4; nf++) {
            short8 vb0 = *(const short8*)&Vt[nf * 16 + lrow][lk];
            short8 vb1 = *(const short8*)&Vt[nf * 16 + lrow][32 + lk];
            O[nf] = __builtin_amdgcn_mfma_f32_16x16x32_bf16(pa0, vb0, O[nf], 0, 0, 0);
            O[nf] = __builtin_amdgcn_mfma_f32_16x16x32_bf16(pa1, vb1, O[nf], 0, 0, 0);
        }
    }

#pragma unroll
    for (int nf = 0; nf < 4; nf++) {
#pragma unroll
        for (int j = 0; j < 4; j++) {
            float o = O[nf][j] / lsum[j];
            out[((size_t)b * S_ + q0 + w * 16 + lgrp * 4 + j) * H_ + nf * 16 + lrow] = o;
        }
    }
}

// ---------------------------------------------------------------------------
extern "C" void kernel_launch(void* const* d_in, const int* in_sizes, int n_in,
                              void* d_out, int out_size, void* d_ws, size_t ws_size,
                              hipStream_t stream) {
    const float* x  = (const float*)d_in[0];
    const float* wq = (const float*)d_in[1];
    const float* wk = (const float*)d_in[2];
    const float* wv = (const float*)d_in[3];
    float* out = (float*)d_out;

    char* ws = (char*)d_ws;
    const size_t WT_BYTES  = (size_t)192 * 1024 * 2;
    const size_t QKV_BYTES = (size_t)B_ * S_ * H_ * 2;
    short* Wt = (short*)ws;
    short* qb = (short*)(ws + WT_BYTES);
    short* kb = (short*)(ws + WT_BYTES + QKV_BYTES);
    short* vb = (short*)(ws + WT_BYTES + 2 * QKV_BYTES);

    wprep_kernel<<<48, 256, 0, stream>>>(wq, wk, wv, Wt);
    qkv_proj_kernel<<<512, 256, 0, stream>>>(x, Wt, qb, kb, vb);
    attn_kernel<<<256, 256, 0, stream>>>(qb, kb, vb, out);
}

// Round 3
// 79.386 us; speedup vs baseline: 2.3598x; 1.4138x over previous
//
#include <hip/hip_runtime.h>
#include <hip/hip_bf16.h>

#define B_ 8
#define S_ 2048
#define E_ 1024
#define H_ 64
#define LOG2E 1.4426950408889634f

typedef __attribute__((ext_vector_type(8))) short short8;
typedef __attribute__((ext_vector_type(4))) float floatx4;
typedef unsigned int u32;

static __device__ __forceinline__ short f2bf(float f) {
    union { float f; unsigned u; } a; a.f = f;
    unsigned r = a.u + 0x7FFF + ((a.u >> 16) & 1);
    return (short)(r >> 16);
}

static __device__ __forceinline__ void gl_lds16(const short* g, short* l) {
    __builtin_amdgcn_global_load_lds(
        (const __attribute__((address_space(1))) u32*)(g),
        (__attribute__((address_space(3))) u32*)(l),
        16, 0, 0);
}

// ---------------------------------------------------------------------------
// Kernel 1: weights -> bf16, tiled per K-panel [16][192][64] with XOR chunk
// swizzle pre-applied in global so global_load_lds(linear) + swizzled ds_read
// is conflict-free.
// ---------------------------------------------------------------------------
__global__ __launch_bounds__(256) void wprep_kernel(
        const float* __restrict__ wq, const float* __restrict__ wk,
        const float* __restrict__ wv, short* __restrict__ Wt) {
    __shared__ short Ws[64][73];
    int bid = blockIdx.x;            // 48 blocks: m = bid>>4, e-chunk = bid&15
    int m  = bid >> 4;
    int ec = bid & 15;
    const float* src = (m == 0) ? wq : ((m == 1) ? wk : wv);
    int t = threadIdx.x;

    {
        int er = t >> 2;
        int hc = (t & 3) * 16;
        const float* sp = src + (size_t)(ec * 64 + er) * H_ + hc;
        floatx4 v0 = *(const floatx4*)(sp);
        floatx4 v1 = *(const floatx4*)(sp + 4);
        floatx4 v2 = *(const floatx4*)(sp + 8);
        floatx4 v3 = *(const floatx4*)(sp + 12);
#pragma unroll
        for (int j = 0; j < 4; j++) Ws[er][hc + j]      = f2bf(v0[j]);
#pragma unroll
        for (int j = 0; j < 4; j++) Ws[er][hc + 4 + j]  = f2bf(v1[j]);
#pragma unroll
        for (int j = 0; j < 4; j++) Ws[er][hc + 8 + j]  = f2bf(v2[j]);
#pragma unroll
        for (int j = 0; j < 4; j++) Ws[er][hc + 12 + j] = f2bf(v3[j]);
    }
    __syncthreads();

    {
        int h  = t >> 2;
        int eo = (t & 3) * 16;
        int row = m * 64 + h;
        short* obase = Wt + (size_t)ec * 12288 + (size_t)row * 64;
#pragma unroll
        for (int g = 0; g < 2; g++) {
            short8 o;
#pragma unroll
            for (int jj = 0; jj < 8; jj++) o[jj] = Ws[eo + g * 8 + jj][h];
            int chunk = ((eo >> 3) + g) ^ (row & 7);
            *(short8*)(obase + chunk * 8) = o;
        }
    }
}

// ---------------------------------------------------------------------------
// Kernel 2: QKV projection GEMM (unchanged this round).
// ---------------------------------------------------------------------------
__global__ __launch_bounds__(256) void qkv_proj_kernel(
        const float* __restrict__ x, const short* __restrict__ Wt,
        short* __restrict__ qb, short* __restrict__ kb, short* __restrict__ vb) {
    __shared__ short Wlds[2][12288];

    int tid  = threadIdx.x;
    int lane = tid & 63;
    int w    = tid >> 6;
    int lrow = lane & 15;
    int lgrp = lane >> 4;
    int lk   = lgrp * 8;

    int wrow = (w >> 1) * 16;
    int wcol = (w & 1) * 96;
    int rowbase = blockIdx.x * 32;

    const float* xp = x + (size_t)(rowbase + wrow + lrow) * E_ + lk;

    floatx4 acc[6];
#pragma unroll
    for (int i = 0; i < 6; i++) acc[i] = (floatx4){0.f, 0.f, 0.f, 0.f};

    {
        const short* p = Wt + (size_t)0 * 12288 + w * 512 + lane * 8;
        short* l = &Wlds[0][w * 512];
#pragma unroll
        for (int i = 0; i < 6; i++) gl_lds16(p + i * 2048, l + i * 2048);
    }
    floatx4 xa0 = *(const floatx4*)(xp);
    floatx4 xa1 = *(const floatx4*)(xp + 4);
    floatx4 xb0 = *(const floatx4*)(xp + 32);
    floatx4 xb1 = *(const floatx4*)(xp + 36);

    __syncthreads();

    for (int ks = 0; ks < 16; ks++) {
        int cur = ks & 1;
        if (ks < 15) {
            const short* p = Wt + (size_t)(ks + 1) * 12288 + w * 512 + lane * 8;
            short* l = &Wlds[cur ^ 1][w * 512];
#pragma unroll
            for (int i = 0; i < 6; i++) gl_lds16(p + i * 2048, l + i * 2048);
        }
        short8 a0, a1;
        a0[0] = f2bf(xa0[0]); a0[1] = f2bf(xa0[1]); a0[2] = f2bf(xa0[2]); a0[3] = f2bf(xa0[3]);
        a0[4] = f2bf(xa1[0]); a0[5] = f2bf(xa1[1]); a0[6] = f2bf(xa1[2]); a0[7] = f2bf(xa1[3]);
        a1[0] = f2bf(xb0[0]); a1[1] = f2bf(xb0[1]); a1[2] = f2bf(xb0[2]); a1[3] = f2bf(xb0[3]);
        a1[4] = f2bf(xb1[0]); a1[5] = f2bf(xb1[1]); a1[6] = f2bf(xb1[2]); a1[7] = f2bf(xb1[3]);
        if (ks < 15) {
            const float* xn = xp + (ks + 1) * 64;
            xa0 = *(const floatx4*)(xn);
            xa1 = *(const floatx4*)(xn + 4);
            xb0 = *(const floatx4*)(xn + 32);
            xb1 = *(const floatx4*)(xn + 36);
        }
        const short* base = &Wlds[cur][0];
#pragma unroll
        for (int nf = 0; nf < 6; nf++) {
            int row = wcol + nf * 16 + lrow;
            int c0  = lgrp ^ (row & 7);
            short8 b0 = *(const short8*)(base + row * 64 + c0 * 8);
            short8 b1 = *(const short8*)(base + row * 64 + (c0 ^ 4) * 8);
            acc[nf] = __builtin_amdgcn_mfma_f32_16x16x32_bf16(a0, b0, acc[nf], 0, 0, 0);
            acc[nf] = __builtin_amdgcn_mfma_f32_16x16x32_bf16(a1, b1, acc[nf], 0, 0, 0);
        }
        __syncthreads();
    }

    int rrow = lgrp * 4;
#pragma unroll
    for (int nf = 0; nf < 6; nf++) {
        int col = wcol + nf * 16 + lrow;
        short* dst = (col < 64) ? qb : ((col < 128) ? kb : vb);
        int cc = col & 63;
#pragma unroll
        for (int j = 0; j < 4; j++) {
            dst[(size_t)(rowbase + wrow + rrow + j) * H_ + cc] = f2bf(acc[nf][j]);
        }
    }
}

// ---------------------------------------------------------------------------
// Kernel 3: causal flash attention, split-KV.
// Grid = B x 32 qtiles x nsplit.  Block = 4 waves, 64 q rows.
// Each split covers a chunk of the causal KV range; writes UNNORMALIZED
// partial O plus per-row (m, l) to ws.  Empty splits write m=-1e30, l=0.
// ---------------------------------------------------------------------------
__global__ __launch_bounds__(256) void attn_kernel(
        const short* __restrict__ qb, const short* __restrict__ kb,
        const short* __restrict__ vb, float* __restrict__ Opart,
        float* __restrict__ ml, int nsplit) {
    __shared__ __align__(16) short Vt[64][72];
    __shared__ __align__(16) short Ps[4][16][72];

    int tid  = threadIdx.x;
    int lane = tid & 63;
    int w    = tid >> 6;
    int lrow = lane & 15;
    int lgrp = lane >> 4;
    int lk   = lgrp * 8;

    int sp = blockIdx.x % nsplit;
    int bq = blockIdx.x / nsplit;
    int qt = bq & 31;
    int b  = bq >> 5;
    int q0 = qt * 64;

    int T = qt + 1;
    int chunk = (T + nsplit - 1) / nsplit;
    int t0 = sp * chunk;
    int t1 = (T < t0 + chunk) ? T : (t0 + chunk);

    // rows this lane's fragment group owns (for ml/epilogue)
    int qrow_o = q0 + w * 16 + lgrp * 4;       // + j
    size_t mlrow = (size_t)sp * 16384 + (size_t)b * S_ + qrow_o;

    if (t0 >= T) {
        // empty split: mark with m=-1e30, l=0 (weight becomes exactly 0)
        if (lrow == 0) {
#pragma unroll
            for (int j = 0; j < 4; j++) {
                ml[(mlrow + j) * 2 + 0] = -1e30f;
                ml[(mlrow + j) * 2 + 1] = 0.f;
            }
        }
        return;
    }

    int qrow = q0 + w * 16 + lrow;
    const short* qptr = qb + ((size_t)b * S_ + qrow) * H_;
    short8 qf0 = *(const short8*)(qptr + lk);
    short8 qf1 = *(const short8*)(qptr + 32 + lk);

    floatx4 O[4];
#pragma unroll
    for (int nf = 0; nf < 4; nf++) O[nf] = (floatx4){0.f, 0.f, 0.f, 0.f};
    float m[4], lsum[4];
#pragma unroll
    for (int j = 0; j < 4; j++) { m[j] = -1e30f; lsum[j] = 0.f; }

    const short* kbase = kb + (size_t)b * S_ * H_;
    const short* vbase = vb + (size_t)b * S_ * H_;

    for (int t = t0; t < t1; t++) {
        int kv0 = t * 64;
        __syncthreads();

        {
            int kvr = tid >> 2;
            int hs  = (tid & 3) * 16;
            const short* vp = vbase + (size_t)(kv0 + kvr) * H_ + hs;
            short8 v0 = *(const short8*)vp;
            short8 v1 = *(const short8*)(vp + 8);
#pragma unroll
            for (int c = 0; c < 8; c++) Vt[hs + c][kvr] = v0[c];
#pragma unroll
            for (int c = 0; c < 8; c++) Vt[hs + 8 + c][kvr] = v1[c];
        }

        floatx4 s[4];
#pragma unroll
        for (int nf = 0; nf < 4; nf++) {
            const short* kp = kbase + (size_t)(kv0 + nf * 16 + lrow) * H_ + lk;
            short8 b0 = *(const short8*)kp;
            short8 b1 = *(const short8*)(kp + 32);
            floatx4 a = (floatx4){0.f, 0.f, 0.f, 0.f};
            a = __builtin_amdgcn_mfma_f32_16x16x32_bf16(qf0, b0, a, 0, 0, 0);
            a = __builtin_amdgcn_mfma_f32_16x16x32_bf16(qf1, b1, a, 0, 0, 0);
            s[nf] = a;
        }
#pragma unroll
        for (int nf = 0; nf < 4; nf++)
#pragma unroll
            for (int j = 0; j < 4; j++) s[nf][j] *= 0.03125f;

        if (t == qt) {
#pragma unroll
            for (int nf = 0; nf < 4; nf++) {
                int kvidx = kv0 + nf * 16 + lrow;
#pragma unroll
                for (int j = 0; j < 4; j++) {
                    int qidx = q0 + w * 16 + lgrp * 4 + j;
                    if (kvidx > qidx) s[nf][j] = -1e30f;
                }
            }
        }

        float alpha[4];
#pragma unroll
        for (int j = 0; j < 4; j++) {
            float mx = fmaxf(fmaxf(s[0][j], s[1][j]), fmaxf(s[2][j], s[3][j]));
#pragma unroll
            for (int off = 1; off < 16; off <<= 1)
                mx = fmaxf(mx, __shfl_xor(mx, off));
            float mn = fmaxf(m[j], mx);
            alpha[j] = exp2f((m[j] - mn) * LOG2E);
            m[j] = mn;
            float ps = 0.f;
#pragma unroll
            for (int nf = 0; nf < 4; nf++) {
                float p = exp2f((s[nf][j] - mn) * LOG2E);
                s[nf][j] = p;
                ps += p;
            }
#pragma unroll
            for (int off = 1; off < 16; off <<= 1)
                ps += __shfl_xor(ps, off);
            lsum[j] = lsum[j] * alpha[j] + ps;
        }

#pragma unroll
        for (int nf = 0; nf < 4; nf++) {
#pragma unroll
            for (int j = 0; j < 4; j++) {
                Ps[w][lgrp * 4 + j][nf * 16 + lrow] = f2bf(s[nf][j]);
                O[nf][j] *= alpha[j];
            }
        }
        __syncthreads();

        short8 pa0 = *(const short8*)&Ps[w][lrow][lk];
        short8 pa1 = *(const short8*)&Ps[w][lrow][32 + lk];
#pragma unroll
        for (int nf = 0; nf < 4; nf++) {
            short8 vb0 = *(const short8*)&Vt[nf * 16 + lrow][lk];
            short8 vb1 = *(const short8*)&Vt[nf * 16 + lrow][32 + lk];
            O[nf] = __builtin_amdgcn_mfma_f32_16x16x32_bf16(pa0, vb0, O[nf], 0, 0, 0);
            O[nf] = __builtin_amdgcn_mfma_f32_16x16x32_bf16(pa1, vb1, O[nf], 0, 0, 0);
        }
    }

    // epilogue: unnormalized partial O + (m, l)
    if (lrow == 0) {
#pragma unroll
        for (int j = 0; j < 4; j++) {
            ml[(mlrow + j) * 2 + 0] = m[j];
            ml[(mlrow + j) * 2 + 1] = lsum[j];
        }
    }
#pragma unroll
    for (int nf = 0; nf < 4; nf++) {
#pragma unroll
        for (int j = 0; j < 4; j++) {
            Opart[(mlrow + j) * H_ + nf * 16 + lrow] = O[nf][j];
        }
    }
}

// ---------------------------------------------------------------------------
// Kernel 4: combine split partials.  grid = 4096 blocks x 256 thr;
// each block does 4 q-rows x 64 h.
// ---------------------------------------------------------------------------
__global__ __launch_bounds__(256) void combine_kernel(
        const float* __restrict__ Opart, const float* __restrict__ ml,
        float* __restrict__ out, int nsplit) {
    int t = threadIdx.x;
    int row = blockIdx.x * 4 + (t >> 6);   // 0..16383  (b*S + q)
    int h = t & 63;

    float M = -1e30f;
    for (int s = 0; s < nsplit; s++)
        M = fmaxf(M, ml[((size_t)s * 16384 + row) * 2]);

    float L = 0.f, acc = 0.f;
    for (int s = 0; s < nsplit; s++) {
        float ms = ml[((size_t)s * 16384 + row) * 2];
        float ls = ml[((size_t)s * 16384 + row) * 2 + 1];
        float wgt = exp2f((ms - M) * LOG2E);
        L += wgt * ls;
        acc += wgt * Opart[((size_t)s * 16384 + row) * H_ + h];
    }
    out[(size_t)row * H_ + h] = acc / L;
}

// ---------------------------------------------------------------------------
extern "C" void kernel_launch(void* const* d_in, const int* in_sizes, int n_in,
                              void* d_out, int out_size, void* d_ws, size_t ws_size,
                              hipStream_t stream) {
    const float* x  = (const float*)d_in[0];
    const float* wq = (const float*)d_in[1];
    const float* wk = (const float*)d_in[2];
    const float* wv = (const float*)d_in[3];
    float* out = (float*)d_out;

    char* ws = (char*)d_ws;
    const size_t WT_BYTES  = (size_t)192 * 1024 * 2;            // 393216
    const size_t QKV_BYTES = (size_t)B_ * S_ * H_ * 2;          // 2097152
    const size_t ML_BYTES  = (size_t)8 * 16384 * 2 * 4;         // reserve for 8 splits
    const size_t OP_UNIT   = (size_t)16384 * H_ * 4;            // 4 MB per split

    short* Wt = (short*)ws;
    short* qb = (short*)(ws + WT_BYTES);
    short* kb = (short*)(ws + WT_BYTES + QKV_BYTES);
    short* vb = (short*)(ws + WT_BYTES + 2 * QKV_BYTES);
    char*  mlp = ws + WT_BYTES + 3 * QKV_BYTES;
    char*  opp = mlp + ML_BYTES;
    size_t fixed = WT_BYTES + 3 * QKV_BYTES + ML_BYTES;

    int nsplit = 1;
    if (ws_size >= fixed + 8 * OP_UNIT) nsplit = 8;
    else if (ws_size >= fixed + 4 * OP_UNIT) nsplit = 4;
    else if (ws_size >= fixed + 2 * OP_UNIT) nsplit = 2;

    wprep_kernel<<<48, 256, 0, stream>>>(wq, wk, wv, Wt);
    qkv_proj_kernel<<<512, 256, 0, stream>>>(x, Wt, qb, kb, vb);
    attn_kernel<<<8 * 32 * nsplit, 256, 0, stream>>>(qb, kb, vb,
            (float*)opp, (float*)mlp, nsplit);
    combine_kernel<<<4096, 256, 0, stream>>>((const float*)opp,
            (const float*)mlp, out, nsplit);
}

// Round 5
// 75.024 us; speedup vs baseline: 2.4970x; 1.0581x over previous
//
#include <hip/hip_runtime.h>
#include <hip/hip_bf16.h>

#define B_ 8
#define S_ 2048
#define E_ 1024
#define H_ 64
#define LOG2E 1.4426950408889634f

typedef __attribute__((ext_vector_type(8))) short short8;
typedef __attribute__((ext_vector_type(4))) float floatx4;
typedef unsigned int u32;

static __device__ __forceinline__ short f2bf(float f) {
    union { float f; unsigned u; } a; a.f = f;
    unsigned r = a.u + 0x7FFF + ((a.u >> 16) & 1);
    return (short)(r >> 16);
}
static __device__ __forceinline__ float bf2f(short s) {
    union { unsigned u; float f; } a; a.u = ((u32)(unsigned short)s) << 16;
    return a.f;
}
static __device__ __forceinline__ void gl_lds16(const void* g, void* l) {
    __builtin_amdgcn_global_load_lds(
        (const __attribute__((address_space(1))) u32*)(g),
        (__attribute__((address_space(3))) u32*)(l),
        16, 0, 0);
}

// ---------------------------------------------------------------------------
// Kernel 1: weights -> bf16, tiled per K-panel [16][192][64] with XOR chunk
// swizzle pre-applied in global: element (ks,row,col) at
// ks*12288 + row*64 + ((col>>3)^(row&7))*8 + (col&7).
// ---------------------------------------------------------------------------
__global__ __launch_bounds__(256) void wprep_kernel(
        const float* __restrict__ wq, const float* __restrict__ wk,
        const float* __restrict__ wv, short* __restrict__ Wt) {
    __shared__ short Ws[64][73];
    int bid = blockIdx.x;            // 48 blocks: m = bid>>4, e-chunk = bid&15
    int m  = bid >> 4;
    int ec = bid & 15;
    const float* src = (m == 0) ? wq : ((m == 1) ? wk : wv);
    int t = threadIdx.x;
    {
        int er = t >> 2;
        int hc = (t & 3) * 16;
        const float* sp = src + (size_t)(ec * 64 + er) * H_ + hc;
        floatx4 v0 = *(const floatx4*)(sp);
        floatx4 v1 = *(const floatx4*)(sp + 4);
        floatx4 v2 = *(const floatx4*)(sp + 8);
        floatx4 v3 = *(const floatx4*)(sp + 12);
#pragma unroll
        for (int j = 0; j < 4; j++) Ws[er][hc + j]      = f2bf(v0[j]);
#pragma unroll
        for (int j = 0; j < 4; j++) Ws[er][hc + 4 + j]  = f2bf(v1[j]);
#pragma unroll
        for (int j = 0; j < 4; j++) Ws[er][hc + 8 + j]  = f2bf(v2[j]);
#pragma unroll
        for (int j = 0; j < 4; j++) Ws[er][hc + 12 + j] = f2bf(v3[j]);
    }
    __syncthreads();
    {
        int h  = t >> 2;
        int eo = (t & 3) * 16;
        int row = m * 64 + h;
        short* obase = Wt + (size_t)ec * 12288 + (size_t)row * 64;
#pragma unroll
        for (int g = 0; g < 2; g++) {
            short8 o;
#pragma unroll
            for (int jj = 0; jj < 8; jj++) o[jj] = Ws[eo + g * 8 + jj][h];
            int chunk = ((eo >> 3) + g) ^ (row & 7);
            *(short8*)(obase + chunk * 8) = o;
        }
    }
}

// ---------------------------------------------------------------------------
// Kernel 2: QKV projection GEMM.  M=16384, K=1024, N=192, BM=32, BK=64.
// W and x staged via global_load_lds (16B/lane) with XOR-swizzled global
// source; fragment reads are bank-balanced ds_read_b128.  Double-buffered.
// ---------------------------------------------------------------------------
__global__ __launch_bounds__(256) void qkv_proj_kernel(
        const float* __restrict__ x, const short* __restrict__ Wt,
        short* __restrict__ qb, short* __restrict__ kb, short* __restrict__ vb) {
    __shared__ short Wlds[2][12288];   // 2 x 24 KB
    __shared__ float Xlds[2][2048];    // 2 x  8 KB

    int tid  = threadIdx.x;
    int lane = tid & 63;
    int w    = tid >> 6;
    int lrow = lane & 15;
    int lgrp = lane >> 4;

    int wrow = (w >> 1) * 16;          // 0 / 16
    int wcol = (w & 1) * 96;           // 0 / 96
    int rowbase = blockIdx.x * 32;

    floatx4 acc[6];
#pragma unroll
    for (int i = 0; i < 6; i++) acc[i] = (floatx4){0.f, 0.f, 0.f, 0.f};

#define STAGE_QKV(KSRC, BUF) do {                                            \
        const short* pw = Wt + (size_t)(KSRC) * 12288 + w * 512 + lane * 8;  \
        short* lw = &Wlds[BUF][w * 512];                                     \
        _Pragma("unroll")                                                    \
        for (int i = 0; i < 6; i++) gl_lds16(pw + i * 2048, lw + i * 2048);  \
        _Pragma("unroll")                                                    \
        for (int it = 0; it < 2; it++) {                                     \
            int j = it * 256 + w * 64 + lane;                                \
            int r = j >> 4; int c = j & 15;                                  \
            const float* px = x + (size_t)(rowbase + r) * E_ +               \
                              (KSRC) * 64 + ((c ^ (r & 7)) << 2);            \
            float* lx = &Xlds[BUF][(it * 256 + w * 64) * 4];                 \
            gl_lds16(px, lx);                                                \
        } } while (0)

    STAGE_QKV(0, 0);
    __syncthreads();

    int r_loc = wrow + lrow;
    int s7 = r_loc & 7;

    for (int ks = 0; ks < 16; ks++) {
        int cur = ks & 1;
        if (ks < 15) STAGE_QKV(ks + 1, cur ^ 1);

        const float* xb = &Xlds[cur][r_loc * 64];
        floatx4 f0 = *(const floatx4*)(xb + (((2 * lgrp)     ^ s7) << 2));
        floatx4 f1 = *(const floatx4*)(xb + (((2 * lgrp + 1) ^ s7) << 2));
        floatx4 f2 = *(const floatx4*)(xb + (((8 + 2 * lgrp) ^ s7) << 2));
        floatx4 f3 = *(const floatx4*)(xb + (((9 + 2 * lgrp) ^ s7) << 2));
        short8 a0, a1;
        a0[0] = f2bf(f0[0]); a0[1] = f2bf(f0[1]); a0[2] = f2bf(f0[2]); a0[3] = f2bf(f0[3]);
        a0[4] = f2bf(f1[0]); a0[5] = f2bf(f1[1]); a0[6] = f2bf(f1[2]); a0[7] = f2bf(f1[3]);
        a1[0] = f2bf(f2[0]); a1[1] = f2bf(f2[1]); a1[2] = f2bf(f2[2]); a1[3] = f2bf(f2[3]);
        a1[4] = f2bf(f3[0]); a1[5] = f2bf(f3[1]); a1[6] = f2bf(f3[2]); a1[7] = f2bf(f3[3]);

        const short* wb = &Wlds[cur][0];
#pragma unroll
        for (int nf = 0; nf < 6; nf++) {
            int row = wcol + nf * 16 + lrow;
            int c0  = lgrp ^ (row & 7);
            short8 b0 = *(const short8*)(wb + row * 64 + c0 * 8);
            short8 b1 = *(const short8*)(wb + row * 64 + (c0 ^ 4) * 8);
            acc[nf] = __builtin_amdgcn_mfma_f32_16x16x32_bf16(a0, b0, acc[nf], 0, 0, 0);
            acc[nf] = __builtin_amdgcn_mfma_f32_16x16x32_bf16(a1, b1, acc[nf], 0, 0, 0);
        }
        __syncthreads();
    }
#undef STAGE_QKV

    // --- epilogue: transpose through LDS, coalesced short8 stores ---
    {
        short* sl = &Wlds[0][w * 1664];    // per-wave [16][104]
#pragma unroll
        for (int nf = 0; nf < 6; nf++)
#pragma unroll
            for (int j = 0; j < 4; j++)
                sl[(lgrp * 4 + j) * 104 + nf * 16 + lrow] = f2bf(acc[nf][j]);
        __syncthreads();
#pragma unroll
        for (int i = 0; i < 3; i++) {
            int mIdx = lane + 64 * i;          // 0..191 = 16 rows x 12 chunks
            int rloc = mIdx / 12;
            int cm   = mIdx % 12;
            short8 v = *(const short8*)(sl + rloc * 104 + cm * 8);
            int grow = rowbase + wrow + rloc;
            int gcol = wcol + cm * 8;
            short* dst = (gcol < 64) ? qb : ((gcol < 128) ? kb : vb);
            int cc = gcol & 63;
            *(short8*)(dst + (size_t)grow * H_ + cc) = v;
        }
    }
}

// ---------------------------------------------------------------------------
// Kernel 3: causal flash attention, split-KV, K staged via swizzled
// global_load_lds (double-buffered).  Grid = B x 32 qtiles x nsplit.
// Partial O written UNNORMALIZED as bf16 (+ f32 m,l per row).
// ---------------------------------------------------------------------------
__global__ __launch_bounds__(256) void attn_kernel(
        const short* __restrict__ qb, const short* __restrict__ kb,
        const short* __restrict__ vb, short* __restrict__ Opart,
        float* __restrict__ ml, int nsplit) {
    __shared__ __align__(16) short Klds[2][4096];   // 2 x 8 KB
    __shared__ __align__(16) short Vt[64][72];      // V^T [h][kv], padded
    __shared__ __align__(16) short Ps[4][16][72];   // per-wave P (and O) tile

    int tid  = threadIdx.x;
    int lane = tid & 63;
    int w    = tid >> 6;
    int lrow = lane & 15;
    int lgrp = lane >> 4;
    int lk   = lgrp * 8;

    int sp = blockIdx.x % nsplit;
    int bq = blockIdx.x / nsplit;
    int qt = bq & 31;
    int b  = bq >> 5;
    int q0 = qt * 64;

    int T = qt + 1;
    int chunk = (T + nsplit - 1) / nsplit;
    int t0 = sp * chunk;
    int t1 = (T < t0 + chunk) ? T : (t0 + chunk);

    size_t mlrow = (size_t)sp * 16384 + (size_t)b * S_ + q0 + w * 16 + lgrp * 4;

    if (t0 >= T) {
        if (lrow == 0) {
#pragma unroll
            for (int j = 0; j < 4; j++) {
                ml[(mlrow + j) * 2 + 0] = -1e30f;
                ml[(mlrow + j) * 2 + 1] = 0.f;
            }
        }
        return;
    }

    const short* kbase = kb + (size_t)b * S_ * H_;
    const short* vbase = vb + (size_t)b * S_ * H_;

    int qrow = q0 + w * 16 + lrow;
    const short* qptr = qb + ((size_t)b * S_ + qrow) * H_;
    short8 qf0 = *(const short8*)(qptr + lk);
    short8 qf1 = *(const short8*)(qptr + 32 + lk);

#define STAGE_K(TT, BUF) do {                                                 \
        int kv0s = (TT) * 64;                                                 \
        _Pragma("unroll")                                                     \
        for (int it = 0; it < 2; it++) {                                      \
            int j = it * 256 + w * 64 + lane;                                 \
            int r = j >> 3; int c = j & 7;                                    \
            const short* pk = kbase + (size_t)(kv0s + r) * H_ +               \
                              ((c ^ (r & 7)) << 3);                           \
            short* lkp = &Klds[BUF][(it * 256 + w * 64) * 8];                 \
            gl_lds16(pk, lkp);                                                \
        } } while (0)

    int kvr = tid >> 2;
    int hs  = (tid & 3) * 16;

    STAGE_K(t0, 0);
    const short* vp0 = vbase + (size_t)(t0 * 64 + kvr) * H_ + hs;
    short8 vr0 = *(const short8*)vp0;
    short8 vr1 = *(const short8*)(vp0 + 8);

    floatx4 O[4];
#pragma unroll
    for (int nf = 0; nf < 4; nf++) O[nf] = (floatx4){0.f, 0.f, 0.f, 0.f};
    float m[4], lsum[4];
#pragma unroll
    for (int j = 0; j < 4; j++) { m[j] = -1e30f; lsum[j] = 0.f; }

    for (int t = t0; t < t1; t++) {
        int cur = (t - t0) & 1;
        int kv0 = t * 64;
        __syncthreads();                 // K(t) staged; Vt/Ps free

        if (t + 1 < t1) STAGE_K(t + 1, cur ^ 1);

        // write V(t) from regs (transposed)
#pragma unroll
        for (int c = 0; c < 8; c++) Vt[hs + c][kvr] = vr0[c];
#pragma unroll
        for (int c = 0; c < 8; c++) Vt[hs + 8 + c][kvr] = vr1[c];

        // prefetch V(t+1)
        if (t + 1 < t1) {
            const short* vp = vbase + (size_t)((t + 1) * 64 + kvr) * H_ + hs;
            vr0 = *(const short8*)vp;
            vr1 = *(const short8*)(vp + 8);
        }

        // --- S = (Q K^T) * scale, K frags from swizzled LDS ---
        floatx4 s[4];
#pragma unroll
        for (int nf = 0; nf < 4; nf++) {
            int r = nf * 16 + lrow;
            int c0 = lgrp ^ (r & 7);
            const short* kp = &Klds[cur][r * 64];
            short8 b0 = *(const short8*)(kp + c0 * 8);
            short8 b1 = *(const short8*)(kp + (c0 ^ 4) * 8);
            floatx4 a = (floatx4){0.f, 0.f, 0.f, 0.f};
            a = __builtin_amdgcn_mfma_f32_16x16x32_bf16(qf0, b0, a, 0, 0, 0);
            a = __builtin_amdgcn_mfma_f32_16x16x32_bf16(qf1, b1, a, 0, 0, 0);
            s[nf] = a;
        }
#pragma unroll
        for (int nf = 0; nf < 4; nf++)
#pragma unroll
            for (int j = 0; j < 4; j++) s[nf][j] *= 0.03125f;

        if (t == qt) {
#pragma unroll
            for (int nf = 0; nf < 4; nf++) {
                int kvidx = kv0 + nf * 16 + lrow;
#pragma unroll
                for (int j = 0; j < 4; j++) {
                    int qidx = q0 + w * 16 + lgrp * 4 + j;
                    if (kvidx > qidx) s[nf][j] = -1e30f;
                }
            }
        }

        float alpha[4];
#pragma unroll
        for (int j = 0; j < 4; j++) {
            float mx = fmaxf(fmaxf(s[0][j], s[1][j]), fmaxf(s[2][j], s[3][j]));
#pragma unroll
            for (int off = 1; off < 16; off <<= 1)
                mx = fmaxf(mx, __shfl_xor(mx, off));
            float mn = fmaxf(m[j], mx);
            alpha[j] = exp2f((m[j] - mn) * LOG2E);
            m[j] = mn;
            float ps = 0.f;
#pragma unroll
            for (int nf = 0; nf < 4; nf++) {
                float p = exp2f((s[nf][j] - mn) * LOG2E);
                s[nf][j] = p;
                ps += p;
            }
#pragma unroll
            for (int off = 1; off < 16; off <<= 1)
                ps += __shfl_xor(ps, off);
            lsum[j] = lsum[j] * alpha[j] + ps;
        }

#pragma unroll
        for (int nf = 0; nf < 4; nf++) {
#pragma unroll
            for (int j = 0; j < 4; j++) {
                Ps[w][lgrp * 4 + j][nf * 16 + lrow] = f2bf(s[nf][j]);
                O[nf][j] *= alpha[j];
            }
        }
        __syncthreads();                 // Ps + Vt visible

        short8 pa0 = *(const short8*)&Ps[w][lrow][lk];
        short8 pa1 = *(const short8*)&Ps[w][lrow][32 + lk];
#pragma unroll
        for (int nf = 0; nf < 4; nf++) {
            short8 vb0 = *(const short8*)&Vt[nf * 16 + lrow][lk];
            short8 vb1 = *(const short8*)&Vt[nf * 16 + lrow][32 + lk];
            O[nf] = __builtin_amdgcn_mfma_f32_16x16x32_bf16(pa0, vb0, O[nf], 0, 0, 0);
            O[nf] = __builtin_amdgcn_mfma_f32_16x16x32_bf16(pa1, vb1, O[nf], 0, 0, 0);
        }
    }
#undef STAGE_K

    // --- epilogue: m,l + transposed coalesced bf16 O stores ---
    if (lrow == 0) {
#pragma unroll
        for (int j = 0; j < 4; j++) {
            ml[(mlrow + j) * 2 + 0] = m[j];
            ml[(mlrow + j) * 2 + 1] = lsum[j];
        }
    }
    __syncthreads();                     // all PV reads of Ps done
#pragma unroll
    for (int nf = 0; nf < 4; nf++)
#pragma unroll
        for (int j = 0; j < 4; j++)
            Ps[w][lgrp * 4 + j][nf * 16 + lrow] = f2bf(O[nf][j]);
    __syncthreads();
    {
        // FIX (round-3 bug): cover ALL 64 cols — 16 rows x 4 lane-chunks x 16 cols
        int row = lane >> 2;
        int c   = lane & 3;
        short8 ov0 = *(const short8*)&Ps[w][row][c * 16];
        short8 ov1 = *(const short8*)&Ps[w][row][c * 16 + 8];
        size_t grow = (size_t)sp * 16384 + (size_t)b * S_ + q0 + w * 16 + row;
        *(short8*)(Opart + grow * H_ + c * 16) = ov0;
        *(short8*)(Opart + grow * H_ + c * 16 + 8) = ov1;
    }
}

// ---------------------------------------------------------------------------
// Kernel 4: combine split partials (bf16 partial O).
// ---------------------------------------------------------------------------
__global__ __launch_bounds__(256) void combine_kernel(
        const short* __restrict__ Opart, const float* __restrict__ ml,
        float* __restrict__ out, int nsplit) {
    int t = threadIdx.x;
    int row = blockIdx.x * 4 + (t >> 6);   // 0..16383
    int h = t & 63;

    float M = -1e30f;
    for (int s = 0; s < nsplit; s++)
        M = fmaxf(M, ml[((size_t)s * 16384 + row) * 2]);

    float L = 0.f, acc = 0.f;
    for (int s = 0; s < nsplit; s++) {
        float ms = ml[((size_t)s * 16384 + row) * 2];
        float ls = ml[((size_t)s * 16384 + row) * 2 + 1];
        float wgt = exp2f((ms - M) * LOG2E);
        L += wgt * ls;
        acc += wgt * bf2f(Opart[((size_t)s * 16384 + row) * H_ + h]);
    }
    out[(size_t)row * H_ + h] = acc / L;
}

// ---------------------------------------------------------------------------
extern "C" void kernel_launch(void* const* d_in, const int* in_sizes, int n_in,
                              void* d_out, int out_size, void* d_ws, size_t ws_size,
                              hipStream_t stream) {
    const float* x  = (const float*)d_in[0];
    const float* wq = (const float*)d_in[1];
    const float* wk = (const float*)d_in[2];
    const float* wv = (const float*)d_in[3];
    float* out = (float*)d_out;

    char* ws = (char*)d_ws;
    const size_t WT_BYTES  = (size_t)192 * 1024 * 2;            // 384 KB
    const size_t QKV_BYTES = (size_t)B_ * S_ * H_ * 2;          // 2 MB each
    const size_t ML_BYTES  = (size_t)8 * 16384 * 2 * 4;         // 1 MB (8 splits)
    const size_t OP_UNIT   = (size_t)16384 * H_ * 2;            // 2 MB per split (bf16)

    short* Wt = (short*)ws;
    short* qb = (short*)(ws + WT_BYTES);
    short* kb = (short*)(ws + WT_BYTES + QKV_BYTES);
    short* vb = (short*)(ws + WT_BYTES + 2 * QKV_BYTES);
    char*  mlp = ws + WT_BYTES + 3 * QKV_BYTES;
    char*  opp = mlp + ML_BYTES;
    size_t fixed = WT_BYTES + 3 * QKV_BYTES + ML_BYTES;

    int nsplit = 1;
    if (ws_size >= fixed + 8 * OP_UNIT) nsplit = 8;
    else if (ws_size >= fixed + 4 * OP_UNIT) nsplit = 4;
    else if (ws_size >= fixed + 2 * OP_UNIT) nsplit = 2;

    wprep_kernel<<<48, 256, 0, stream>>>(wq, wk, wv, Wt);
    qkv_proj_kernel<<<512, 256, 0, stream>>>(x, Wt, qb, kb, vb);
    attn_kernel<<<8 * 32 * nsplit, 256, 0, stream>>>(qb, kb, vb,
            (short*)opp, (float*)mlp, nsplit);
    combine_kernel<<<4096, 256, 0, stream>>>((const short*)opp,
            (const float*)mlp, out, nsplit);
}

// Round 6
// 69.750 us; speedup vs baseline: 2.6858x; 1.0756x over previous
//
#include <hip/hip_runtime.h>
#include <hip/hip_bf16.h>

#define B_ 8
#define S_ 2048
#define E_ 1024
#define H_ 64
#define LOG2E 1.4426950408889634f

typedef __attribute__((ext_vector_type(8))) short short8;
typedef __attribute__((ext_vector_type(4))) float floatx4;
typedef unsigned int u32;

static __device__ __forceinline__ short f2bf(float f) {
    union { float f; unsigned u; } a; a.f = f;
    unsigned r = a.u + 0x7FFF + ((a.u >> 16) & 1);
    return (short)(r >> 16);
}
static __device__ __forceinline__ float bf2f(short s) {
    union { unsigned u; float f; } a; a.u = ((u32)(unsigned short)s) << 16;
    return a.f;
}
static __device__ __forceinline__ void gl_lds16(const void* g, void* l) {
    __builtin_amdgcn_global_load_lds(
        (const __attribute__((address_space(1))) u32*)(g),
        (__attribute__((address_space(3))) u32*)(l),
        16, 0, 0);
}

// ---------------------------------------------------------------------------
// Kernel 1: weights -> bf16, tiled per K-panel [16][192][64] with XOR chunk
// swizzle pre-applied in global: element (ks,row,col) at
// ks*12288 + row*64 + ((col>>3)^(row&7))*8 + (col&7).
// ---------------------------------------------------------------------------
__global__ __launch_bounds__(256) void wprep_kernel(
        const float* __restrict__ wq, const float* __restrict__ wk,
        const float* __restrict__ wv, short* __restrict__ Wt) {
    __shared__ short Ws[64][73];
    int bid = blockIdx.x;            // 48 blocks: m = bid>>4, e-chunk = bid&15
    int m  = bid >> 4;
    int ec = bid & 15;
    const float* src = (m == 0) ? wq : ((m == 1) ? wk : wv);
    int t = threadIdx.x;
    {
        int er = t >> 2;
        int hc = (t & 3) * 16;
        const float* sp = src + (size_t)(ec * 64 + er) * H_ + hc;
        floatx4 v0 = *(const floatx4*)(sp);
        floatx4 v1 = *(const floatx4*)(sp + 4);
        floatx4 v2 = *(const floatx4*)(sp + 8);
        floatx4 v3 = *(const floatx4*)(sp + 12);
#pragma unroll
        for (int j = 0; j < 4; j++) Ws[er][hc + j]      = f2bf(v0[j]);
#pragma unroll
        for (int j = 0; j < 4; j++) Ws[er][hc + 4 + j]  = f2bf(v1[j]);
#pragma unroll
        for (int j = 0; j < 4; j++) Ws[er][hc + 8 + j]  = f2bf(v2[j]);
#pragma unroll
        for (int j = 0; j < 4; j++) Ws[er][hc + 12 + j] = f2bf(v3[j]);
    }
    __syncthreads();
    {
        int h  = t >> 2;
        int eo = (t & 3) * 16;
        int row = m * 64 + h;
        short* obase = Wt + (size_t)ec * 12288 + (size_t)row * 64;
#pragma unroll
        for (int g = 0; g < 2; g++) {
            short8 o;
#pragma unroll
            for (int jj = 0; jj < 8; jj++) o[jj] = Ws[eo + g * 8 + jj][h];
            int chunk = ((eo >> 3) + g) ^ (row & 7);
            *(short8*)(obase + chunk * 8) = o;
        }
    }
}

// ---------------------------------------------------------------------------
// Kernel 2: QKV projection GEMM, REG-STAGED write-late (T14).
// M=16384, K=1024, N=192, BM=32, BK=64, grid 512 (2 blocks/CU), 4 waves.
// Per step: loads(ks+1)->regs FIRST, compute(ks) from LDS (no VMEM->LDS
// outstanding during ds_reads => no forced vmcnt drain), then cvt+ds_write
// (ks+1), ONE barrier.  x stored bf16 in padded [32][72] rows (bank-balanced);
// W keeps the wprep pre-swizzled layout, linear LDS copy, swizzled reads.
// ---------------------------------------------------------------------------
__global__ __launch_bounds__(256) void qkv_proj_kernel(
        const float* __restrict__ x, const short* __restrict__ Wt,
        short* __restrict__ qb, short* __restrict__ kb, short* __restrict__ vb) {
    __shared__ __align__(16) short Wlds[2][12288];   // 2 x 24 KB
    __shared__ __align__(16) short Xlds[2][2304];    // 2 x 32*72 bf16 = 4.5 KB

    int tid  = threadIdx.x;
    int lane = tid & 63;
    int w    = tid >> 6;
    int lrow = lane & 15;
    int lgrp = lane >> 4;

    int wrow = (w >> 1) * 16;          // 0 / 16
    int wcol = (w & 1) * 96;           // 0 / 96
    int rowbase = blockIdx.x * 32;

    // staging mapping: thread -> (x row, 16-float chunk) and W offset
    int xr = tid >> 3;                 // 0..31
    int xc = tid & 7;                  // 0..7 chunks of 8 floats
    const float* xgp = x + (size_t)(rowbase + xr) * E_ + xc * 8;
    const short* wgp = Wt + (size_t)w * 512 + lane * 8;

    floatx4 acc[6];
#pragma unroll
    for (int i = 0; i < 6; i++) acc[i] = (floatx4){0.f, 0.f, 0.f, 0.f};

    floatx4 xf0, xf1;
    short8 wv0, wv1, wv2, wv3, wv4, wv5;

    // ---- prologue: load + stage step 0 into buf 0 ----
    xf0 = *(const floatx4*)(xgp);
    xf1 = *(const floatx4*)(xgp + 4);
    wv0 = *(const short8*)(wgp);
    wv1 = *(const short8*)(wgp + 2048);
    wv2 = *(const short8*)(wgp + 4096);
    wv3 = *(const short8*)(wgp + 6144);
    wv4 = *(const short8*)(wgp + 8192);
    wv5 = *(const short8*)(wgp + 10240);
    {
        short8 xs;
        xs[0] = f2bf(xf0[0]); xs[1] = f2bf(xf0[1]); xs[2] = f2bf(xf0[2]); xs[3] = f2bf(xf0[3]);
        xs[4] = f2bf(xf1[0]); xs[5] = f2bf(xf1[1]); xs[6] = f2bf(xf1[2]); xs[7] = f2bf(xf1[3]);
        *(short8*)&Xlds[0][xr * 72 + xc * 8] = xs;
        short* lw = &Wlds[0][w * 512 + lane * 8];
        *(short8*)(lw)         = wv0;
        *(short8*)(lw + 2048)  = wv1;
        *(short8*)(lw + 4096)  = wv2;
        *(short8*)(lw + 6144)  = wv3;
        *(short8*)(lw + 8192)  = wv4;
        *(short8*)(lw + 10240) = wv5;
    }
    __syncthreads();

    for (int ks = 0; ks < 16; ks++) {
        int cur = ks & 1;

        // issue next-step global loads -> registers (early)
        if (ks < 15) {
            const float* xn = xgp + (ks + 1) * 64;
            xf0 = *(const floatx4*)(xn);
            xf1 = *(const floatx4*)(xn + 4);
            const short* wn = wgp + (size_t)(ks + 1) * 12288;
            wv0 = *(const short8*)(wn);
            wv1 = *(const short8*)(wn + 2048);
            wv2 = *(const short8*)(wn + 4096);
            wv3 = *(const short8*)(wn + 6144);
            wv4 = *(const short8*)(wn + 8192);
            wv5 = *(const short8*)(wn + 10240);
        }

        // ---- compute step ks from buf[cur] (pure LDS + MFMA) ----
        const short* xb = &Xlds[cur][(wrow + lrow) * 72];
        short8 a0 = *(const short8*)(xb + lgrp * 8);
        short8 a1 = *(const short8*)(xb + 32 + lgrp * 8);
        const short* wb = &Wlds[cur][0];
#pragma unroll
        for (int nf = 0; nf < 6; nf++) {
            int row = wcol + nf * 16 + lrow;
            int c0  = lgrp ^ (row & 7);
            short8 b0 = *(const short8*)(wb + row * 64 + c0 * 8);
            short8 b1 = *(const short8*)(wb + row * 64 + (c0 ^ 4) * 8);
            acc[nf] = __builtin_amdgcn_mfma_f32_16x16x32_bf16(a0, b0, acc[nf], 0, 0, 0);
            acc[nf] = __builtin_amdgcn_mfma_f32_16x16x32_bf16(a1, b1, acc[nf], 0, 0, 0);
        }

        // ---- write-late: stage step ks+1 into buf[cur^1] ----
        if (ks < 15) {
            short8 xs;
            xs[0] = f2bf(xf0[0]); xs[1] = f2bf(xf0[1]); xs[2] = f2bf(xf0[2]); xs[3] = f2bf(xf0[3]);
            xs[4] = f2bf(xf1[0]); xs[5] = f2bf(xf1[1]); xs[6] = f2bf(xf1[2]); xs[7] = f2bf(xf1[3]);
            *(short8*)&Xlds[cur ^ 1][xr * 72 + xc * 8] = xs;
            short* lw = &Wlds[cur ^ 1][w * 512 + lane * 8];
            *(short8*)(lw)         = wv0;
            *(short8*)(lw + 2048)  = wv1;
            *(short8*)(lw + 4096)  = wv2;
            *(short8*)(lw + 6144)  = wv3;
            *(short8*)(lw + 8192)  = wv4;
            *(short8*)(lw + 10240) = wv5;
        }
        __syncthreads();
    }

    // --- epilogue: transpose through LDS, coalesced short8 stores ---
    {
        short* sl = &Wlds[0][w * 1664];    // per-wave [16][104]
#pragma unroll
        for (int nf = 0; nf < 6; nf++)
#pragma unroll
            for (int j = 0; j < 4; j++)
                sl[(lgrp * 4 + j) * 104 + nf * 16 + lrow] = f2bf(acc[nf][j]);
        __syncthreads();
#pragma unroll
        for (int i = 0; i < 3; i++) {
            int mIdx = lane + 64 * i;          // 0..191 = 16 rows x 12 chunks
            int rloc = mIdx / 12;
            int cm   = mIdx % 12;
            short8 v = *(const short8*)(sl + rloc * 104 + cm * 8);
            int grow = rowbase + wrow + rloc;
            int gcol = wcol + cm * 8;
            short* dst = (gcol < 64) ? qb : ((gcol < 128) ? kb : vb);
            int cc = gcol & 63;
            *(short8*)(dst + (size_t)grow * H_ + cc) = v;
        }
    }
}

// ---------------------------------------------------------------------------
// Kernel 3: causal flash attention, split-KV (unchanged control).
// ---------------------------------------------------------------------------
__global__ __launch_bounds__(256) void attn_kernel(
        const short* __restrict__ qb, const short* __restrict__ kb,
        const short* __restrict__ vb, short* __restrict__ Opart,
        float* __restrict__ ml, int nsplit) {
    __shared__ __align__(16) short Klds[2][4096];   // 2 x 8 KB
    __shared__ __align__(16) short Vt[64][72];      // V^T [h][kv], padded
    __shared__ __align__(16) short Ps[4][16][72];   // per-wave P (and O) tile

    int tid  = threadIdx.x;
    int lane = tid & 63;
    int w    = tid >> 6;
    int lrow = lane & 15;
    int lgrp = lane >> 4;
    int lk   = lgrp * 8;

    int sp = blockIdx.x % nsplit;
    int bq = blockIdx.x / nsplit;
    int qt = bq & 31;
    int b  = bq >> 5;
    int q0 = qt * 64;

    int T = qt + 1;
    int chunk = (T + nsplit - 1) / nsplit;
    int t0 = sp * chunk;
    int t1 = (T < t0 + chunk) ? T : (t0 + chunk);

    size_t mlrow = (size_t)sp * 16384 + (size_t)b * S_ + q0 + w * 16 + lgrp * 4;

    if (t0 >= T) {
        if (lrow == 0) {
#pragma unroll
            for (int j = 0; j < 4; j++) {
                ml[(mlrow + j) * 2 + 0] = -1e30f;
                ml[(mlrow + j) * 2 + 1] = 0.f;
            }
        }
        return;
    }

    const short* kbase = kb + (size_t)b * S_ * H_;
    const short* vbase = vb + (size_t)b * S_ * H_;

    int qrow = q0 + w * 16 + lrow;
    const short* qptr = qb + ((size_t)b * S_ + qrow) * H_;
    short8 qf0 = *(const short8*)(qptr + lk);
    short8 qf1 = *(const short8*)(qptr + 32 + lk);

#define STAGE_K(TT, BUF) do {                                                 \
        int kv0s = (TT) * 64;                                                 \
        _Pragma("unroll")                                                     \
        for (int it = 0; it < 2; it++) {                                      \
            int j = it * 256 + w * 64 + lane;                                 \
            int r = j >> 3; int c = j & 7;                                    \
            const short* pk = kbase + (size_t)(kv0s + r) * H_ +               \
                              ((c ^ (r & 7)) << 3);                           \
            short* lkp = &Klds[BUF][(it * 256 + w * 64) * 8];                 \
            gl_lds16(pk, lkp);                                                \
        } } while (0)

    int kvr = tid >> 2;
    int hs  = (tid & 3) * 16;

    STAGE_K(t0, 0);
    const short* vp0 = vbase + (size_t)(t0 * 64 + kvr) * H_ + hs;
    short8 vr0 = *(const short8*)vp0;
    short8 vr1 = *(const short8*)(vp0 + 8);

    floatx4 O[4];
#pragma unroll
    for (int nf = 0; nf < 4; nf++) O[nf] = (floatx4){0.f, 0.f, 0.f, 0.f};
    float m[4], lsum[4];
#pragma unroll
    for (int j = 0; j < 4; j++) { m[j] = -1e30f; lsum[j] = 0.f; }

    for (int t = t0; t < t1; t++) {
        int cur = (t - t0) & 1;
        int kv0 = t * 64;
        __syncthreads();                 // K(t) staged; Vt/Ps free

        if (t + 1 < t1) STAGE_K(t + 1, cur ^ 1);

        // write V(t) from regs (transposed)
#pragma unroll
        for (int c = 0; c < 8; c++) Vt[hs + c][kvr] = vr0[c];
#pragma unroll
        for (int c = 0; c < 8; c++) Vt[hs + 8 + c][kvr] = vr1[c];

        // prefetch V(t+1)
        if (t + 1 < t1) {
            const short* vp = vbase + (size_t)((t + 1) * 64 + kvr) * H_ + hs;
            vr0 = *(const short8*)vp;
            vr1 = *(const short8*)(vp + 8);
        }

        // --- S = (Q K^T) * scale, K frags from swizzled LDS ---
        floatx4 s[4];
#pragma unroll
        for (int nf = 0; nf < 4; nf++) {
            int r = nf * 16 + lrow;
            int c0 = lgrp ^ (r & 7);
            const short* kp = &Klds[cur][r * 64];
            short8 b0 = *(const short8*)(kp + c0 * 8);
            short8 b1 = *(const short8*)(kp + (c0 ^ 4) * 8);
            floatx4 a = (floatx4){0.f, 0.f, 0.f, 0.f};
            a = __builtin_amdgcn_mfma_f32_16x16x32_bf16(qf0, b0, a, 0, 0, 0);
            a = __builtin_amdgcn_mfma_f32_16x16x32_bf16(qf1, b1, a, 0, 0, 0);
            s[nf] = a;
        }
#pragma unroll
        for (int nf = 0; nf < 4; nf++)
#pragma unroll
            for (int j = 0; j < 4; j++) s[nf][j] *= 0.03125f;

        if (t == qt) {
#pragma unroll
            for (int nf = 0; nf < 4; nf++) {
                int kvidx = kv0 + nf * 16 + lrow;
#pragma unroll
                for (int j = 0; j < 4; j++) {
                    int qidx = q0 + w * 16 + lgrp * 4 + j;
                    if (kvidx > qidx) s[nf][j] = -1e30f;
                }
            }
        }

        float alpha[4];
#pragma unroll
        for (int j = 0; j < 4; j++) {
            float mx = fmaxf(fmaxf(s[0][j], s[1][j]), fmaxf(s[2][j], s[3][j]));
#pragma unroll
            for (int off = 1; off < 16; off <<= 1)
                mx = fmaxf(mx, __shfl_xor(mx, off));
            float mn = fmaxf(m[j], mx);
            alpha[j] = exp2f((m[j] - mn) * LOG2E);
            m[j] = mn;
            float ps = 0.f;
#pragma unroll
            for (int nf = 0; nf < 4; nf++) {
                float p = exp2f((s[nf][j] - mn) * LOG2E);
                s[nf][j] = p;
                ps += p;
            }
#pragma unroll
            for (int off = 1; off < 16; off <<= 1)
                ps += __shfl_xor(ps, off);
            lsum[j] = lsum[j] * alpha[j] + ps;
        }

#pragma unroll
        for (int nf = 0; nf < 4; nf++) {
#pragma unroll
            for (int j = 0; j < 4; j++) {
                Ps[w][lgrp * 4 + j][nf * 16 + lrow] = f2bf(s[nf][j]);
                O[nf][j] *= alpha[j];
            }
        }
        __syncthreads();                 // Ps + Vt visible

        short8 pa0 = *(const short8*)&Ps[w][lrow][lk];
        short8 pa1 = *(const short8*)&Ps[w][lrow][32 + lk];
#pragma unroll
        for (int nf = 0; nf < 4; nf++) {
            short8 vb0 = *(const short8*)&Vt[nf * 16 + lrow][lk];
            short8 vb1 = *(const short8*)&Vt[nf * 16 + lrow][32 + lk];
            O[nf] = __builtin_amdgcn_mfma_f32_16x16x32_bf16(pa0, vb0, O[nf], 0, 0, 0);
            O[nf] = __builtin_amdgcn_mfma_f32_16x16x32_bf16(pa1, vb1, O[nf], 0, 0, 0);
        }
    }
#undef STAGE_K

    // --- epilogue: m,l + transposed coalesced bf16 O stores ---
    if (lrow == 0) {
#pragma unroll
        for (int j = 0; j < 4; j++) {
            ml[(mlrow + j) * 2 + 0] = m[j];
            ml[(mlrow + j) * 2 + 1] = lsum[j];
        }
    }
    __syncthreads();                     // all PV reads of Ps done
#pragma unroll
    for (int nf = 0; nf < 4; nf++)
#pragma unroll
        for (int j = 0; j < 4; j++)
            Ps[w][lgrp * 4 + j][nf * 16 + lrow] = f2bf(O[nf][j]);
    __syncthreads();
    {
        // full 16x64 coverage: 16 rows x 4 lane-chunks x 16 cols
        int row = lane >> 2;
        int c   = lane & 3;
        short8 ov0 = *(const short8*)&Ps[w][row][c * 16];
        short8 ov1 = *(const short8*)&Ps[w][row][c * 16 + 8];
        size_t grow = (size_t)sp * 16384 + (size_t)b * S_ + q0 + w * 16 + row;
        *(short8*)(Opart + grow * H_ + c * 16) = ov0;
        *(short8*)(Opart + grow * H_ + c * 16 + 8) = ov1;
    }
}

// ---------------------------------------------------------------------------
// Kernel 4: combine split partials (bf16 partial O).
// ---------------------------------------------------------------------------
__global__ __launch_bounds__(256) void combine_kernel(
        const short* __restrict__ Opart, const float* __restrict__ ml,
        float* __restrict__ out, int nsplit) {
    int t = threadIdx.x;
    int row = blockIdx.x * 4 + (t >> 6);   // 0..16383
    int h = t & 63;

    float M = -1e30f;
    for (int s = 0; s < nsplit; s++)
        M = fmaxf(M, ml[((size_t)s * 16384 + row) * 2]);

    float L = 0.f, acc = 0.f;
    for (int s = 0; s < nsplit; s++) {
        float ms = ml[((size_t)s * 16384 + row) * 2];
        float ls = ml[((size_t)s * 16384 + row) * 2 + 1];
        float wgt = exp2f((ms - M) * LOG2E);
        L += wgt * ls;
        acc += wgt * bf2f(Opart[((size_t)s * 16384 + row) * H_ + h]);
    }
    out[(size_t)row * H_ + h] = acc / L;
}

// ---------------------------------------------------------------------------
extern "C" void kernel_launch(void* const* d_in, const int* in_sizes, int n_in,
                              void* d_out, int out_size, void* d_ws, size_t ws_size,
                              hipStream_t stream) {
    const float* x  = (const float*)d_in[0];
    const float* wq = (const float*)d_in[1];
    const float* wk = (const float*)d_in[2];
    const float* wv = (const float*)d_in[3];
    float* out = (float*)d_out;

    char* ws = (char*)d_ws;
    const size_t WT_BYTES  = (size_t)192 * 1024 * 2;            // 384 KB
    const size_t QKV_BYTES = (size_t)B_ * S_ * H_ * 2;          // 2 MB each
    const size_t ML_BYTES  = (size_t)8 * 16384 * 2 * 4;         // 1 MB (8 splits)
    const size_t OP_UNIT   = (size_t)16384 * H_ * 2;            // 2 MB per split (bf16)

    short* Wt = (short*)ws;
    short* qb = (short*)(ws + WT_BYTES);
    short* kb = (short*)(ws + WT_BYTES + QKV_BYTES);
    short* vb = (short*)(ws + WT_BYTES + 2 * QKV_BYTES);
    char*  mlp = ws + WT_BYTES + 3 * QKV_BYTES;
    char*  opp = mlp + ML_BYTES;
    size_t fixed = WT_BYTES + 3 * QKV_BYTES + ML_BYTES;

    int nsplit = 1;
    if (ws_size >= fixed + 8 * OP_UNIT) nsplit = 8;
    else if (ws_size >= fixed + 4 * OP_UNIT) nsplit = 4;
    else if (ws_size >= fixed + 2 * OP_UNIT) nsplit = 2;

    wprep_kernel<<<48, 256, 0, stream>>>(wq, wk, wv, Wt);
    qkv_proj_kernel<<<512, 256, 0, stream>>>(x, Wt, qb, kb, vb);
    attn_kernel<<<8 * 32 * nsplit, 256, 0, stream>>>(qb, kb, vb,
            (short*)opp, (float*)mlp, nsplit);
    combine_kernel<<<4096, 256, 0, stream>>>((const short*)opp,
            (const float*)mlp, out, nsplit);
}